// Round 11
// baseline (186.736 us; speedup 1.0000x reference)
//
#include <hip/hip_runtime.h>
#include <hip/hip_bf16.h>

// Flash-attention fwd, fp32 in/out, bf16 MFMA compute.
// B=64 (batch*heads), L=1024, D=64. scale=1/sqrt(512). mask(int32)!=0 -> -1e9.
// R11: MAX-TLP configuration. Single-buffered K/V LDS (18.4 KB) + VGPR<=64
//      (__launch_bounds__(256,8)) -> target 8 blocks/CU, 32 waves/CU.
//      Latency hiding via block-level TLP instead of (never-materialized)
//      register prefetch. 2 barriers/tile. R10's verified compute kept:
//      swapped QK^T, in-register P exchange, defer-max, packed mask.

typedef __attribute__((ext_vector_type(4))) float f32x4;
typedef __attribute__((ext_vector_type(8))) short bf16x8;
typedef __attribute__((ext_vector_type(4))) short short4v;

constexpr int B_ = 64;
constexpr int L_ = 1024;
constexpr int D_ = 64;
constexpr int QBLK = 64;     // q rows per block (4 waves x 16)
constexpr int KV = 64;       // keys per tile
constexpr int NKV = L_ / KV; // 16 tiles
constexpr int STR = 72;      // shorts per LDS row (64 + 8 pad)
constexpr float SC2 = 0.06376003f;   // (1/sqrt(512)) * log2(e)
constexpr float NEG = -1e9f;
constexpr float THR = 8.0f;          // defer-max threshold (log2 units)

__device__ inline short f2bf(float f) {
  __hip_bfloat16 h = __float2bfloat16(f);
  short s; __builtin_memcpy(&s, &h, 2);
  return s;
}
__device__ inline unsigned int pk2(float a, float b) {
  return (unsigned int)(unsigned short)f2bf(a)
       | ((unsigned int)(unsigned short)f2bf(b) << 16);
}

__global__ __launch_bounds__(256, 8) void attn_fwd(
    const float* __restrict__ Q, const float* __restrict__ K,
    const float* __restrict__ V, const int* __restrict__ M,
    float* __restrict__ O)
{
  __shared__ short k_lds[KV][STR];    // 9.2 KB
  __shared__ short vt_lds[D_][STR];   // 9.2 KB   -> 18.4 KB total, 8 blk/CU

  const int tid  = threadIdx.x;
  const int w    = tid >> 6;
  const int lane = tid & 63;
  const int g    = lane >> 4;
  const int c    = lane & 15;
  const int b    = blockIdx.y;
  const int q0   = blockIdx.x * QBLK;

  // ---- Q fragment (B operand of swapped QK^T): col=c -> q-row w*16+c
  bf16x8 qf[2];
  {
    const float* qp = Q + ((size_t)b * L_ + q0 + w * 16 + c) * D_ + g * 8;
#pragma unroll
    for (int ks = 0; ks < 2; ++ks) {
      f32x4 x0 = *(const f32x4*)(qp + ks * 32);
      f32x4 x1 = *(const f32x4*)(qp + ks * 32 + 4);
      bf16x8 t;
      t[0] = f2bf(x0[0]); t[1] = f2bf(x0[1]); t[2] = f2bf(x0[2]); t[3] = f2bf(x0[3]);
      t[4] = f2bf(x1[0]); t[5] = f2bf(x1[1]); t[6] = f2bf(x1[2]); t[7] = f2bf(x1[3]);
      qf[ks] = t;
    }
  }

  const float* Kb = K + (size_t)b * L_ * D_;
  const float* Vb = V + (size_t)b * L_ * D_;
  // mask, swapped layout: lane's own row q=w*16+c, keys f*16+4g+0..3 per tile
  const int* mlane = M + (size_t)b * L_ * L_ + (size_t)(q0 + w * 16 + c) * L_ + 4 * g;

  const int vkey4 = (tid & 15) * 4;
  const int vd4   = (tid >> 4) * 4;

  // stage tile t: global fp32 -> cvt -> LDS bf16 (K direct, V transposed 4x4)
  auto stage = [&](int t) {
    const float* ksrc = Kb + (size_t)(t * KV) * D_;
    const float* vsrc = Vb + (size_t)(t * KV) * D_;
    f32x4 kreg[4], vreg[4];
#pragma unroll
    for (int i = 0; i < 4; ++i) {
      kreg[i] = *(const f32x4*)(ksrc + (size_t)(tid + i * 256) * 4);
      vreg[i] = *(const f32x4*)(vsrc + (size_t)(vkey4 + i) * D_ + vd4);
    }
#pragma unroll
    for (int i = 0; i < 4; ++i) {
      const int idx = tid + i * 256;
      const int row = idx >> 4;
      const int d4  = (idx & 15) * 4;
      short4v ks4 = { f2bf(kreg[i][0]), f2bf(kreg[i][1]),
                      f2bf(kreg[i][2]), f2bf(kreg[i][3]) };
      *(short4v*)&k_lds[row][d4] = ks4;
      const int jj = (i + (tid >> 4)) & 3;   // rotated row order (bank spread)
      short4v vt4 = { f2bf(vreg[0][jj]), f2bf(vreg[1][jj]),
                      f2bf(vreg[2][jj]), f2bf(vreg[3][jj]) };
      *(short4v*)&vt_lds[vd4 + jj][vkey4] = vt4;
    }
  };
  auto packm = [&](const int4* lm) {
    unsigned int mp = 0;
#pragma unroll
    for (int f = 0; f < 4; ++f) {
      mp |= (lm[f].x != 0 ? 1u : 0u) << (f * 4 + 0);
      mp |= (lm[f].y != 0 ? 1u : 0u) << (f * 4 + 1);
      mp |= (lm[f].z != 0 ? 1u : 0u) << (f * 4 + 2);
      mp |= (lm[f].w != 0 ? 1u : 0u) << (f * 4 + 3);
    }
    return mp;
  };

  f32x4 acc[4];
#pragma unroll
  for (int i = 0; i < 4; ++i) acc[i] = (f32x4){0.f, 0.f, 0.f, 0.f};
  float m_run = -INFINITY;  // row max (log2 units), row q = w*16+c
  float l_run = 0.f;        // partial sum (this lane's 16 keys/tile)

  stage(0);
  __syncthreads();

  for (int t = 0; t < NKV; ++t) {
    // mask for tile t, direct global->reg (zero reuse; no LDS staging)
    int4 lm[4];
#pragma unroll
    for (int f = 0; f < 4; ++f)
      lm[f] = *(const int4*)(mlane + t * KV + f * 16);
    const unsigned int mc = packm(lm);

    // ---- S^T = K Q^T : C row = key = f*16+g*4+r, col = q = c
    f32x4 sc[4];
#pragma unroll
    for (int f = 0; f < 4; ++f) {
      f32x4 a = (f32x4){0.f, 0.f, 0.f, 0.f};
#pragma unroll
      for (int ks = 0; ks < 2; ++ks) {
        bf16x8 kf = *(const bf16x8*)&k_lds[f * 16 + c][ks * 32 + g * 8];
        a = __builtin_amdgcn_mfma_f32_16x16x32_bf16(kf, qf[ks], a, 0, 0, 0);
      }
      sc[f] = a;
    }

    // ---- mask + scale into log2 domain (bit f*4+r of mc)
#pragma unroll
    for (int f = 0; f < 4; ++f)
#pragma unroll
      for (int r = 0; r < 4; ++r)
        sc[f][r] = ((mc >> (f * 4 + r)) & 1u) ? NEG : sc[f][r] * SC2;

    // ---- online softmax, defer-max: cross-lane work only on growth tiles
    float xl = sc[0][0];
#pragma unroll
    for (int f = 0; f < 4; ++f)
#pragma unroll
      for (int r = 0; r < 4; ++r) xl = fmaxf(xl, sc[f][r]);
    if (!__all(xl <= m_run + THR)) {           // wave-uniform branch
      float x = fmaxf(xl, __shfl_xor(xl, 16, 64));
      x = fmaxf(x, __shfl_xor(x, 32, 64));
      const float m_new = fmaxf(m_run, x);
      const float alpha = exp2f(m_run - m_new);
      l_run *= alpha;
      float ar[4];
#pragma unroll
      for (int r = 0; r < 4; ++r)
        ar[r] = __shfl(alpha, (lane & 48) | (g * 4 + r), 64);
#pragma unroll
      for (int fd = 0; fd < 4; ++fd)
#pragma unroll
        for (int r = 0; r < 4; ++r) acc[fd][r] *= ar[r];
      m_run = m_new;
    }
    float s = 0.f;
#pragma unroll
    for (int f = 0; f < 4; ++f)
#pragma unroll
      for (int r = 0; r < 4; ++r) {
        const float p = exp2f(sc[f][r] - m_run);
        sc[f][r] = p;
        s += p;
      }
    l_run += s;

    // ---- P relayout C->A in-register: two perfect matchings x 4 rounds
    // (verified in R10: absmax 9.77e-4)
    unsigned int pd[4][2];
#pragma unroll
    for (int f = 0; f < 4; ++f) {
      pd[f][0] = pk2(sc[f][0], sc[f][1]);
      pd[f][1] = pk2(sc[f][2], sc[f][3]);
    }
    const int rev2 = ((g & 1) << 1) | (g >> 1);
    const int srcA = rev2 * 16 + c;
    const int srcB = srcA ^ 16;
    const bool podd = (g & 1) != 0;
    const bool gh   = (g >= 2);
    unsigned int d0[4], d1[4];
#pragma unroll
    for (int k = 0; k < 4; ++k) {
      const int fb = 2 * (k >> 1);
      const int hh = k & 1;
      const unsigned int pubA = podd ? pd[fb + 1][hh] : pd[fb + 0][hh];
      const unsigned int pubB = podd ? pd[fb + 0][hh] : pd[fb + 1][hh];
      const unsigned int rvA = (unsigned int)__shfl((int)pubA, srcA, 64);
      const unsigned int rvB = (unsigned int)__shfl((int)pubB, srcB, 64);
      if (k < 2) {
        if (gh) { d0[2 + hh] = rvA; d0[hh] = rvB; }
        else    { d0[hh] = rvA; d0[2 + hh] = rvB; }
      } else {
        if (gh) { d1[2 + hh] = rvA; d1[hh] = rvB; }
        else    { d1[hh] = rvA; d1[2 + hh] = rvB; }
      }
    }
    bf16x8 pa0, pa1;
    __builtin_memcpy(&pa0, d0, 16);
    __builtin_memcpy(&pa1, d1, 16);

    // ---- O += P V
#pragma unroll
    for (int fd = 0; fd < 4; ++fd) {
      bf16x8 vb0 = *(const bf16x8*)&vt_lds[fd * 16 + c][g * 8];
      acc[fd] = __builtin_amdgcn_mfma_f32_16x16x32_bf16(pa0, vb0, acc[fd], 0, 0, 0);
      bf16x8 vb1 = *(const bf16x8*)&vt_lds[fd * 16 + c][32 + g * 8];
      acc[fd] = __builtin_amdgcn_mfma_f32_16x16x32_bf16(pa1, vb1, acc[fd], 0, 0, 0);
    }

    // ---- single-buffer flip: drain readers, restage, publish
    if (t + 1 < NKV) {
      __syncthreads();
      stage(t + 1);
      __syncthreads();
    }
  }

  // ---- epilogue: reduce partial l across the 4-lane group, normalize, store
  float l = l_run;
  l += __shfl_xor(l, 16, 64);
  l += __shfl_xor(l, 32, 64);
  const float li = 1.0f / l;
  float lr[4];
#pragma unroll
  for (int r = 0; r < 4; ++r)
    lr[r] = __shfl(li, (lane & 48) | (g * 4 + r), 64);
  float* orow = O + ((size_t)b * L_ + q0 + w * 16 + g * 4) * D_;
#pragma unroll
  for (int fd = 0; fd < 4; ++fd)
#pragma unroll
    for (int r = 0; r < 4; ++r)
      orow[(size_t)r * D_ + fd * 16 + c] = acc[fd][r] * lr[r];
}

extern "C" void kernel_launch(void* const* d_in, const int* in_sizes, int n_in,
                              void* d_out, int out_size, void* d_ws, size_t ws_size,
                              hipStream_t stream) {
  const float* q = (const float*)d_in[0];
  const float* k = (const float*)d_in[1];
  const float* v = (const float*)d_in[2];
  const int* m = (const int*)d_in[3]; // jax bool shipped as int32
  float* o = (float*)d_out;
  dim3 grid(L_ / QBLK, B_);
  attn_fwd<<<grid, 256, 0, stream>>>(q, k, v, m, o);
}

// Round 12
// 117.226 us; speedup vs baseline: 1.5930x; 1.5930x over previous
//
#include <hip/hip_runtime.h>
#include <hip/hip_bf16.h>

// Flash-attention fwd, fp32 in/out, bf16 MFMA compute.
// B=64 (batch*heads), L=1024, D=64. scale=1/sqrt(512). mask(int32)!=0 -> -1e9.
// R12: INTRA-BLOCK SPLIT-K. 512-thread blocks: waves 0-3 do keys 0-511,
//      waves 4-7 keys 512-1023 (same 64 q-rows). 8192 waves total = 32/CU
//      target (grid was the occupancy cap: 4096 waves = 50% max before).
//      In-block combine via LDS (reuses K/V buffers). Gentle (512,4) bounds —
//      R11 showed hard-forcing causes 32-VGPR spills. Per-half single-buffer
//      K/V; R10's verified compute (swapped QK^T, in-reg P exchange,
//      defer-max, packed mask) unchanged.

typedef __attribute__((ext_vector_type(4))) float f32x4;
typedef __attribute__((ext_vector_type(8))) short bf16x8;
typedef __attribute__((ext_vector_type(4))) short short4v;

constexpr int B_ = 64;
constexpr int L_ = 1024;
constexpr int D_ = 64;
constexpr int QBLK = 64;     // q rows per block (8 waves, 2 halves x 4 waves)
constexpr int KV = 64;       // keys per tile
constexpr int NT_H = 8;      // tiles per half (split-K within block)
constexpr int STR = 72;      // shorts per LDS row (64 + 8 pad)
constexpr float SC2 = 0.06376003f;   // (1/sqrt(512)) * log2(e)
constexpr float NEG = -1e9f;
constexpr float THR = 8.0f;          // defer-max threshold (log2 units)

constexpr int HBUF = 64 * STR * 2;   // 9216 B, one K or V^T buffer

__device__ inline short f2bf(float f) {
  __hip_bfloat16 h = __float2bfloat16(f);
  short s; __builtin_memcpy(&s, &h, 2);
  return s;
}
__device__ inline unsigned int pk2(float a, float b) {
  return (unsigned int)(unsigned short)f2bf(a)
       | ((unsigned int)(unsigned short)f2bf(b) << 16);
}

__global__ __launch_bounds__(512, 4) void attn_fwd(
    const float* __restrict__ Q, const float* __restrict__ K,
    const float* __restrict__ V, const int* __restrict__ M,
    float* __restrict__ O)
{
  // [half][ K(9216) | V^T(9216) ] = 36864 B + 512 B combine m/l tail
  __shared__ __align__(16) unsigned char smem[4 * HBUF + 512];

  const int tid  = threadIdx.x;
  const int w    = tid >> 6;        // 0..7
  const int half = w >> 2;          // 0: keys 0-511, 1: keys 512-1023
  const int w4   = w & 3;           // wave within half; q-rows w4*16..+15
  const int lane = tid & 63;
  const int g    = lane >> 4;
  const int c    = lane & 15;
  const int htid = tid & 255;       // thread id within half
  const int b    = blockIdx.y;
  const int q0   = blockIdx.x * QBLK;

  short (*k_lds)[STR]  = (short(*)[STR])(smem + half * (2 * HBUF));
  short (*vt_lds)[STR] = (short(*)[STR])(smem + half * (2 * HBUF) + HBUF);

  // ---- Q fragment (B operand of swapped QK^T): col=c -> q-row w4*16+c
  bf16x8 qf[2];
  {
    const float* qp = Q + ((size_t)b * L_ + q0 + w4 * 16 + c) * D_ + g * 8;
#pragma unroll
    for (int ks = 0; ks < 2; ++ks) {
      f32x4 x0 = *(const f32x4*)(qp + ks * 32);
      f32x4 x1 = *(const f32x4*)(qp + ks * 32 + 4);
      bf16x8 t;
      t[0] = f2bf(x0[0]); t[1] = f2bf(x0[1]); t[2] = f2bf(x0[2]); t[3] = f2bf(x0[3]);
      t[4] = f2bf(x1[0]); t[5] = f2bf(x1[1]); t[6] = f2bf(x1[2]); t[7] = f2bf(x1[3]);
      qf[ks] = t;
    }
  }

  // this half's K/V/mask base (keys half*512 ..)
  const float* Kb = K + (size_t)b * L_ * D_ + (size_t)half * NT_H * KV * D_;
  const float* Vb = V + (size_t)b * L_ * D_ + (size_t)half * NT_H * KV * D_;
  const int* mlane = M + (size_t)b * L_ * L_
                   + (size_t)(q0 + w4 * 16 + c) * L_ + half * (NT_H * KV) + 4 * g;

  const int vkey4 = (htid & 15) * 4;   // V staging: 4x4 block per thread
  const int vd4   = (htid >> 4) * 4;

  // stage local tile t of this half (K direct; V transposed 4x4 in regs)
  auto stage = [&](int t) {
    const float* ksrc = Kb + (size_t)(t * KV) * D_;
    const float* vsrc = Vb + (size_t)(t * KV) * D_;
#pragma unroll
    for (int i = 0; i < 4; ++i) {        // K: load -> cvt -> write (low regs)
      const int idx = htid + i * 256;
      f32x4 kx = *(const f32x4*)(ksrc + (size_t)idx * 4);
      short4v ks4 = { f2bf(kx[0]), f2bf(kx[1]), f2bf(kx[2]), f2bf(kx[3]) };
      *(short4v*)&k_lds[idx >> 4][(idx & 15) * 4] = ks4;
    }
    f32x4 vreg[4];
#pragma unroll
    for (int i = 0; i < 4; ++i)
      vreg[i] = *(const f32x4*)(vsrc + (size_t)(vkey4 + i) * D_ + vd4);
#pragma unroll
    for (int i = 0; i < 4; ++i) {
      const int jj = (i + (htid >> 4)) & 3;  // rotated row order (bank spread)
      short4v vt4 = { f2bf(vreg[0][jj]), f2bf(vreg[1][jj]),
                      f2bf(vreg[2][jj]), f2bf(vreg[3][jj]) };
      *(short4v*)&vt_lds[vd4 + jj][vkey4] = vt4;
    }
  };

  f32x4 acc[4];
#pragma unroll
  for (int i = 0; i < 4; ++i) acc[i] = (f32x4){0.f, 0.f, 0.f, 0.f};
  float m_run = -INFINITY;  // row max (log2 units), row q = w4*16+c
  float l_run = 0.f;        // partial sum (this lane's 16 keys/tile)

  stage(0);
  __syncthreads();

  for (int t = 0; t < NT_H; ++t) {
    // mask for this tile, direct global->reg, packed to 16 bits
    unsigned int mc = 0;
#pragma unroll
    for (int f = 0; f < 4; ++f) {
      const int4 lm = *(const int4*)(mlane + t * KV + f * 16);
      mc |= (lm.x != 0 ? 1u : 0u) << (f * 4 + 0);
      mc |= (lm.y != 0 ? 1u : 0u) << (f * 4 + 1);
      mc |= (lm.z != 0 ? 1u : 0u) << (f * 4 + 2);
      mc |= (lm.w != 0 ? 1u : 0u) << (f * 4 + 3);
    }

    // ---- S^T = K Q^T : C row = key = f*16+g*4+r, col = q = c
    f32x4 sc[4];
#pragma unroll
    for (int f = 0; f < 4; ++f) {
      f32x4 a = (f32x4){0.f, 0.f, 0.f, 0.f};
#pragma unroll
      for (int ks = 0; ks < 2; ++ks) {
        bf16x8 kf = *(const bf16x8*)&k_lds[f * 16 + c][ks * 32 + g * 8];
        a = __builtin_amdgcn_mfma_f32_16x16x32_bf16(kf, qf[ks], a, 0, 0, 0);
      }
      sc[f] = a;
    }

    // ---- mask + scale into log2 domain (bit f*4+r of mc)
#pragma unroll
    for (int f = 0; f < 4; ++f)
#pragma unroll
      for (int r = 0; r < 4; ++r)
        sc[f][r] = ((mc >> (f * 4 + r)) & 1u) ? NEG : sc[f][r] * SC2;

    // ---- online softmax, defer-max (cross-lane only on growth tiles)
    float xl = sc[0][0];
#pragma unroll
    for (int f = 0; f < 4; ++f)
#pragma unroll
      for (int r = 0; r < 4; ++r) xl = fmaxf(xl, sc[f][r]);
    if (!__all(xl <= m_run + THR)) {           // wave-uniform branch
      float x = fmaxf(xl, __shfl_xor(xl, 16, 64));
      x = fmaxf(x, __shfl_xor(x, 32, 64));
      const float m_new = fmaxf(m_run, x);
      const float alpha = exp2f(m_run - m_new);
      l_run *= alpha;
      float ar[4];
#pragma unroll
      for (int r = 0; r < 4; ++r)
        ar[r] = __shfl(alpha, (lane & 48) | (g * 4 + r), 64);
#pragma unroll
      for (int fd = 0; fd < 4; ++fd)
#pragma unroll
        for (int r = 0; r < 4; ++r) acc[fd][r] *= ar[r];
      m_run = m_new;
    }
    float s = 0.f;
#pragma unroll
    for (int f = 0; f < 4; ++f)
#pragma unroll
      for (int r = 0; r < 4; ++r) {
        const float p = exp2f(sc[f][r] - m_run);
        sc[f][r] = p;
        s += p;
      }
    l_run += s;

    // ---- P relayout C->A in-register: two perfect matchings x 4 rounds
    // (verified R10: absmax 9.77e-4)
    unsigned int pd[4][2];
#pragma unroll
    for (int f = 0; f < 4; ++f) {
      pd[f][0] = pk2(sc[f][0], sc[f][1]);
      pd[f][1] = pk2(sc[f][2], sc[f][3]);
    }
    const int rev2 = ((g & 1) << 1) | (g >> 1);
    const int srcA = rev2 * 16 + c;
    const int srcB = srcA ^ 16;
    const bool podd = (g & 1) != 0;
    const bool gh   = (g >= 2);
    unsigned int d0[4], d1[4];
#pragma unroll
    for (int k = 0; k < 4; ++k) {
      const int fb = 2 * (k >> 1);
      const int hh = k & 1;
      const unsigned int pubA = podd ? pd[fb + 1][hh] : pd[fb + 0][hh];
      const unsigned int pubB = podd ? pd[fb + 0][hh] : pd[fb + 1][hh];
      const unsigned int rvA = (unsigned int)__shfl((int)pubA, srcA, 64);
      const unsigned int rvB = (unsigned int)__shfl((int)pubB, srcB, 64);
      if (k < 2) {
        if (gh) { d0[2 + hh] = rvA; d0[hh] = rvB; }
        else    { d0[hh] = rvA; d0[2 + hh] = rvB; }
      } else {
        if (gh) { d1[2 + hh] = rvA; d1[hh] = rvB; }
        else    { d1[hh] = rvA; d1[2 + hh] = rvB; }
      }
    }
    bf16x8 pa0, pa1;
    __builtin_memcpy(&pa0, d0, 16);
    __builtin_memcpy(&pa1, d1, 16);

    // ---- O += P V
#pragma unroll
    for (int fd = 0; fd < 4; ++fd) {
      bf16x8 vb0 = *(const bf16x8*)&vt_lds[fd * 16 + c][g * 8];
      acc[fd] = __builtin_amdgcn_mfma_f32_16x16x32_bf16(pa0, vb0, acc[fd], 0, 0, 0);
      bf16x8 vb1 = *(const bf16x8*)&vt_lds[fd * 16 + c][32 + g * 8];
      acc[fd] = __builtin_amdgcn_mfma_f32_16x16x32_bf16(pa1, vb1, acc[fd], 0, 0, 0);
    }

    if (t + 1 < NT_H) {
      __syncthreads();      // drain readers of tile t
      stage(t + 1);
      __syncthreads();      // publish tile t+1
    }
  }

  // ==== combine the two key-halves in-block (reuse K/V LDS) ====
  float l = l_run;
  l += __shfl_xor(l, 16, 64);
  l += __shfl_xor(l, 32, 64);          // full row sum for q=c (this half)

  __syncthreads();                      // done reading k/v LDS everywhere
  f32x4* cacc = (f32x4*)smem;           // [4 waves][64 lanes][4] f32x4 = 16 KB
  float2* cml = (float2*)(smem + 4 * HBUF);  // [4][16] rows (m, l)
  if (half == 1) {
#pragma unroll
    for (int fd = 0; fd < 4; ++fd)
      cacc[(w4 * 64 + lane) * 4 + fd] = acc[fd];
    if (g == 0) cml[w4 * 16 + c] = make_float2(m_run, l);
  }
  __syncthreads();
  if (half == 0) {
    const float2 mlB = cml[w4 * 16 + c];
    const float Mx = fmaxf(m_run, mlB.x);
    const float wA = exp2f(m_run - Mx);
    const float wB = exp2f(mlB.x - Mx);
    const float li = 1.0f / (wA * l + wB * mlB.y);  // row q=c
    float arA[4], arB[4], lr[4];
#pragma unroll
    for (int r = 0; r < 4; ++r) {
      const int src = (lane & 48) | (g * 4 + r);
      arA[r] = __shfl(wA, src, 64);
      arB[r] = __shfl(wB, src, 64);
      lr[r]  = __shfl(li, src, 64);
    }
    float* orow = O + ((size_t)b * L_ + q0 + w4 * 16 + g * 4) * D_;
#pragma unroll
    for (int fd = 0; fd < 4; ++fd) {
      const f32x4 ab = cacc[(w4 * 64 + lane) * 4 + fd];
#pragma unroll
      for (int r = 0; r < 4; ++r)
        orow[(size_t)r * D_ + fd * 16 + c] =
            (arA[r] * acc[fd][r] + arB[r] * ab[r]) * lr[r];
    }
  }
}

extern "C" void kernel_launch(void* const* d_in, const int* in_sizes, int n_in,
                              void* d_out, int out_size, void* d_ws, size_t ws_size,
                              hipStream_t stream) {
  const float* q = (const float*)d_in[0];
  const float* k = (const float*)d_in[1];
  const float* v = (const float*)d_in[2];
  const int* m = (const int*)d_in[3]; // jax bool shipped as int32
  float* o = (float*)d_out;
  dim3 grid(L_ / QBLK, B_);
  attn_fwd<<<grid, 512, 0, stream>>>(q, k, v, m, o);
}